// Round 2
// baseline (423.112 us; speedup 1.0000x reference)
//
#include <hip/hip_runtime.h>
#include <hip/hip_bf16.h>
#include <cstdint>
#include <cstddef>

typedef __attribute__((ext_vector_type(8))) short short8;
typedef __attribute__((ext_vector_type(4))) float f32x4;

#define DEVI static __device__ __forceinline__

DEVI unsigned short f2bf(float f) {
  unsigned u = __float_as_uint(f);
  unsigned r = u + 0x7fffu + ((u >> 16) & 1u);
  return (unsigned short)(r >> 16);
}
DEVI float bf2f(unsigned short s) {
  return __uint_as_float(((unsigned)s) << 16);
}
DEVI unsigned pack2(float a, float b) {
  return (unsigned)f2bf(a) | ((unsigned)f2bf(b) << 16);
}

// ---------------------------------------------------------------------------
// prep: convert Wq/Wkv -> wcat bf16 [768][256], Wproj -> wpb bf16 [256][256]
// ---------------------------------------------------------------------------
__global__ void prep_weights(const float* __restrict__ Wq,
                             const float* __restrict__ Wkv,
                             const float* __restrict__ Wp,
                             unsigned short* __restrict__ wcat,
                             unsigned short* __restrict__ wpb) {
  int i = blockIdx.x * 256 + threadIdx.x;   // grid 1024*256 = 262144
  if (i < 196608) {
    float v = (i < 65536) ? Wq[i] : Wkv[i - 65536];
    wcat[i] = f2bf(v);
  } else {
    int j = i - 196608;
    wpb[j] = f2bf(Wp[j]);
  }
}

// ---------------------------------------------------------------------------
// GEMM  C[M x Nout] = A[M x 256] * W[Nout x 256]^T, bf16 MFMA 16x16x32
// MODE 0: A = x (fp32, convert inline), epilogue elu+1 -> Q/K/V bf16
// MODE 1: A = attn (bf16), epilogue + bias -> out fp32
// tile 128x128, BK=64, 256 threads (4 waves, 2x2)
// ---------------------------------------------------------------------------
template<int MODE>
__global__ __launch_bounds__(256) void gemm_bt(
    const void* __restrict__ Aptr,
    const unsigned short* __restrict__ Bw,
    unsigned short* __restrict__ Q,
    unsigned short* __restrict__ Kb,
    unsigned short* __restrict__ Vb,
    float* __restrict__ out,
    const float* __restrict__ bias,
    int ntiles_n) {
  const int bid = blockIdx.x;
  const int bx = bid % ntiles_n;
  const int by = bid / ntiles_n;
  const int brow = by * 128, bcol = bx * 128;
  const int t = threadIdx.x;
  const int lane = t & 63, w = t >> 6;
  const int wm = w >> 1, wn = w & 1;

  __shared__ __align__(16) unsigned char ldsA[128 * 128];  // 128 rows x 64 bf16
  __shared__ __align__(16) unsigned char ldsB[128 * 128];

  f32x4 acc[4][4] = {};

  const int sub = t & 7;       // k-octet (8 bf16 = 16B)
  const int r0 = t >> 3;       // 0..31

  for (int kt = 0; kt < 4; ++kt) {
    // --- stage A ---
    if (MODE == 0) {
      const float* xp = (const float*)Aptr;
#pragma unroll
      for (int p = 0; p < 4; ++p) {
        int row = p * 32 + r0;
        const float4* g =
            (const float4*)(xp + (size_t)(brow + row) * 256 + kt * 64 + sub * 8);
        float4 u0 = g[0], u1 = g[1];
        uint4 u;
        u.x = pack2(u0.x, u0.y);
        u.y = pack2(u0.z, u0.w);
        u.z = pack2(u1.x, u1.y);
        u.w = pack2(u1.z, u1.w);
        int byteo = row * 128 + ((sub * 16) ^ ((row & 7) << 4));
        *(uint4*)(ldsA + byteo) = u;
      }
    } else {
      const unsigned short* ap = (const unsigned short*)Aptr;
#pragma unroll
      for (int p = 0; p < 4; ++p) {
        int row = p * 32 + r0;
        uint4 u = *(const uint4*)(ap + (size_t)(brow + row) * 256 + kt * 64 + sub * 8);
        int byteo = row * 128 + ((sub * 16) ^ ((row & 7) << 4));
        *(uint4*)(ldsA + byteo) = u;
      }
    }
    // --- stage B ---
#pragma unroll
    for (int p = 0; p < 4; ++p) {
      int row = p * 32 + r0;
      uint4 u = *(const uint4*)(Bw + (size_t)(bcol + row) * 256 + kt * 64 + sub * 8);
      int byteo = row * 128 + ((sub * 16) ^ ((row & 7) << 4));
      *(uint4*)(ldsB + byteo) = u;
    }
    __syncthreads();

    const int fr = lane & 15, fq = lane >> 4;
#pragma unroll
    for (int kk = 0; kk < 2; ++kk) {
      int kbyte = kk * 64 + fq * 16;
      short8 af[4], bfr[4];
#pragma unroll
      for (int i = 0; i < 4; ++i) {
        int ra = wm * 64 + i * 16 + fr;
        af[i] = *(const short8*)(ldsA + ra * 128 + (kbyte ^ ((ra & 7) << 4)));
        int rb = wn * 64 + i * 16 + fr;
        bfr[i] = *(const short8*)(ldsB + rb * 128 + (kbyte ^ ((rb & 7) << 4)));
      }
#pragma unroll
      for (int i = 0; i < 4; ++i)
#pragma unroll
        for (int j = 0; j < 4; ++j)
          acc[i][j] = __builtin_amdgcn_mfma_f32_16x16x32_bf16(af[i], bfr[j],
                                                              acc[i][j], 0, 0, 0);
    }
    __syncthreads();
  }

  // --- epilogue ---
  const int fr = lane & 15, fq = lane >> 4;
#pragma unroll
  for (int i = 0; i < 4; ++i) {
#pragma unroll
    for (int j = 0; j < 4; ++j) {
#pragma unroll
      for (int reg = 0; reg < 4; ++reg) {
        int gm = brow + wm * 64 + i * 16 + fq * 4 + reg;
        int gn = bcol + wn * 64 + j * 16 + fr;
        float val = acc[i][j][reg];
        if (MODE == 0) {
          if (gn < 512) val = (val > 0.f) ? (val + 1.f) : __expf(val);
          unsigned short bv = f2bf(val);
          size_t rowoff = (size_t)gm * 256;
          if (gn < 256)
            Q[rowoff + gn] = bv;
          else if (gn < 512)
            Kb[rowoff + gn - 256] = bv;
          else
            Vb[rowoff + gn - 512] = bv;
        } else {
          out[(size_t)gm * 256 + gn] = val + bias[gn];
        }
      }
    }
  }
}

// ---------------------------------------------------------------------------
// ctx partials: per (b,h,chunk) block computes partial k^T v [32x32] and ksum[32]
// grid 512 = 64 bh * 8 chunks, 256 threads
// ---------------------------------------------------------------------------
__global__ __launch_bounds__(256) void ctx_partial(
    const unsigned short* __restrict__ Kb, const unsigned short* __restrict__ Vb,
    float* __restrict__ pctx, float* __restrict__ pksum) {
  const int blk = blockIdx.x;
  const int bh = blk >> 3, chunk = blk & 7;
  const int b = bh >> 3, h = bh & 7;
  const int t = threadIdx.x;
  const size_t rowbase = (size_t)b * 16384 + (size_t)chunk * 2048;
  const int colbase = h * 32;

  __shared__ __align__(16) unsigned short kt_[64][32];
  __shared__ __align__(16) unsigned short vt_[64][32];

  const int d = t >> 3, e = (t & 7) * 4;
  float acc0 = 0.f, acc1 = 0.f, acc2 = 0.f, acc3 = 0.f, ks = 0.f;

  const int nl = t >> 2, dc = (t & 3) * 8;
  for (int pass = 0; pass < 32; ++pass) {
    size_t row = rowbase + pass * 64 + nl;
    *(uint4*)&kt_[nl][dc] = *(const uint4*)(Kb + row * 256 + colbase + dc);
    *(uint4*)&vt_[nl][dc] = *(const uint4*)(Vb + row * 256 + colbase + dc);
    __syncthreads();
#pragma unroll 8
    for (int n = 0; n < 64; ++n) {
      float kv = bf2f(kt_[n][d]);
      if ((t & 7) == 0) ks += kv;
      acc0 += kv * bf2f(vt_[n][e + 0]);
      acc1 += kv * bf2f(vt_[n][e + 1]);
      acc2 += kv * bf2f(vt_[n][e + 2]);
      acc3 += kv * bf2f(vt_[n][e + 3]);
    }
    __syncthreads();
  }
  float* pc = pctx + (size_t)blk * 1024 + t * 4;
  pc[0] = acc0; pc[1] = acc1; pc[2] = acc2; pc[3] = acc3;
  if ((t & 7) == 0) pksum[blk * 32 + d] = ks;
}

// ---------------------------------------------------------------------------
// ctx final reduce: 64 blocks (one per bh)
// ---------------------------------------------------------------------------
__global__ __launch_bounds__(256) void ctx_final(
    const float* __restrict__ pctx, const float* __restrict__ pksum,
    float* __restrict__ ctx, float* __restrict__ ksum) {
  int bh = blockIdx.x;
  int t = threadIdx.x;
  float s0 = 0.f, s1 = 0.f, s2 = 0.f, s3 = 0.f;
  for (int j = 0; j < 8; ++j) {
    const float* p = pctx + ((size_t)(bh * 8 + j) << 10) + t * 4;
    s0 += p[0]; s1 += p[1]; s2 += p[2]; s3 += p[3];
  }
  float* c = ctx + ((size_t)bh << 10) + t * 4;
  c[0] = s0; c[1] = s1; c[2] = s2; c[3] = s3;
  if (t < 32) {
    float s = 0.f;
    for (int j = 0; j < 8; ++j) s += pksum[(bh * 8 + j) * 32 + t];
    ksum[bh * 32 + t] = s;
  }
}

// ---------------------------------------------------------------------------
// attn: Dinv[r][h] = 1/max(sum_d q[r][h,d]*ksum[h,d], 1e-6)  (PER-HEAD!)
//       attn[r][h,e] = Dinv[r][h] * sum_d q[r][h,d]*ctx[h][d][e]
// grid 2048, 256 threads. ctx column held in registers per thread.
// q tile in LDS padded: index (h,d) -> h*36+d  (conflict-free, 16B aligned)
// ---------------------------------------------------------------------------
__global__ __launch_bounds__(256) void attn_kernel(
    const unsigned short* __restrict__ Q, const float* __restrict__ ctx,
    const float* __restrict__ ksum, unsigned short* __restrict__ attnb) {
  const int t = threadIdx.x;
  const size_t row0 = (size_t)blockIdx.x * 64;
  const int b = (int)(row0 >> 14);
  const int h = t >> 5, e = t & 31;

  __shared__ float qf[64][288];
  __shared__ float ksumL[288];
  __shared__ float Dinv_s[64][8];

  // ctx column (d=0..31 for this thread's (h,e)) into registers
  float creg[32];
  const float* cbase = ctx + ((size_t)(b * 8 + h) << 10) + e;
#pragma unroll
  for (int d2 = 0; d2 < 32; ++d2) creg[d2] = cbase[d2 * 32];

  ksumL[h * 36 + e] = ksum[(b * 8 + h) * 32 + e];

  // stage q tile (bf16 -> fp32, padded layout)
  const int rl = t >> 5;
  const int c8 = (t & 31) * 8;
#pragma unroll
  for (int p = 0; p < 8; ++p) {
    int r = p * 8 + rl;
    uint4 u = *(const uint4*)(Q + (row0 + r) * 256 + c8);
    const unsigned short* us = (const unsigned short*)&u;
    float* dst = &qf[r][(c8 >> 5) * 36 + (c8 & 31)];
#pragma unroll
    for (int q2 = 0; q2 < 8; ++q2) dst[q2] = bf2f(us[q2]);
  }
  __syncthreads();

  // per-(row,head) normalizer: 512 values, 2 per thread
#pragma unroll
  for (int ii = 0; ii < 2; ++ii) {
    int idx = t + ii * 256;
    int r = idx >> 3, hh = idx & 7;
    const float* qr = &qf[r][hh * 36];
    const float* ks = &ksumL[hh * 36];
    float s = 0.f;
#pragma unroll
    for (int d2 = 0; d2 < 32; ++d2) s += qr[d2] * ks[d2];
    Dinv_s[r][hh] = 1.f / fmaxf(s, 1e-6f);
  }
  __syncthreads();

  for (int r = 0; r < 64; ++r) {
    const float* qr = &qf[r][h * 36];
    float s = 0.f;
#pragma unroll
    for (int d2 = 0; d2 < 32; ++d2) s += qr[d2] * creg[d2];
    attnb[(row0 + r) * 256 + t] = f2bf(s * Dinv_s[r][h]);
  }
}

// ---------------------------------------------------------------------------
extern "C" void kernel_launch(void* const* d_in, const int* in_sizes, int n_in,
                              void* d_out, int out_size, void* d_ws, size_t ws_size,
                              hipStream_t stream) {
  const float* x = (const float*)d_in[0];
  const float* Wq = (const float*)d_in[1];
  const float* Wkv = (const float*)d_in[2];
  const float* Wproj = (const float*)d_in[3];
  const float* bproj = (const float*)d_in[4];
  float* out = (float*)d_out;

  char* ws = (char*)d_ws;
  unsigned short* Q = (unsigned short*)(ws);                      // 67,108,864 B
  unsigned short* Kb = (unsigned short*)(ws + 67108864);          // 67,108,864 B
  unsigned short* Vb = (unsigned short*)(ws + 134217728);         // 67,108,864 B
  unsigned short* wcat = (unsigned short*)(ws + 201326592);       // 393,216 B
  unsigned short* wpb = (unsigned short*)(ws + 201719808);        // 131,072 B
  float* pctx = (float*)(ws + 201850880);                         // 2,097,152 B
  float* pksum = (float*)(ws + 203948032);                        // 65,536 B
  float* ctx = (float*)(ws + 204013568);                          // 262,144 B
  float* ksum = (float*)(ws + 204275712);                         // 8,192 B
  unsigned short* attnb = Kb;  // reuse K buffer after ctx reduction

  prep_weights<<<1024, 256, 0, stream>>>(Wq, Wkv, Wproj, wcat, wpb);
  gemm_bt<0><<<6144, 256, 0, stream>>>(x, wcat, Q, Kb, Vb, nullptr, nullptr, 6);
  ctx_partial<<<512, 256, 0, stream>>>(Kb, Vb, pctx, pksum);
  ctx_final<<<64, 256, 0, stream>>>(pctx, pksum, ctx, ksum);
  attn_kernel<<<2048, 256, 0, stream>>>(Q, ctx, ksum, attnb);
  gemm_bt<1><<<2048, 256, 0, stream>>>(attnb, wpb, nullptr, nullptr, nullptr, out,
                                       bproj, 2);
}

// Round 3
// 367.883 us; speedup vs baseline: 1.1501x; 1.1501x over previous
//
#include <hip/hip_runtime.h>
#include <hip/hip_bf16.h>
#include <cstdint>
#include <cstddef>

typedef __attribute__((ext_vector_type(8))) short short8;
typedef __attribute__((ext_vector_type(4))) float f32x4;

#define DEVI static __device__ __forceinline__

DEVI unsigned short f2bf(float f) {
  unsigned u = __float_as_uint(f);
  unsigned r = u + 0x7fffu + ((u >> 16) & 1u);
  return (unsigned short)(r >> 16);
}
DEVI float bf2f(unsigned short s) {
  return __uint_as_float(((unsigned)s) << 16);
}
DEVI unsigned pack2(float a, float b) {
  return (unsigned)f2bf(a) | ((unsigned)f2bf(b) << 16);
}

// async global->LDS, 16B per lane; LDS dest = wave-uniform base + lane*16
DEVI void gload16(const void* g, void* l) {
  __builtin_amdgcn_global_load_lds(
      (__attribute__((address_space(1))) void*)g,
      (__attribute__((address_space(3))) void*)l, 16, 0, 0);
}

// ---------------------------------------------------------------------------
// prep: Wq/Wkv -> wcat bf16 [768][256], Wproj -> wpb bf16 [256][256]
// ---------------------------------------------------------------------------
__global__ void prep_weights(const float* __restrict__ Wq,
                             const float* __restrict__ Wkv,
                             const float* __restrict__ Wp,
                             unsigned short* __restrict__ wcat,
                             unsigned short* __restrict__ wpb) {
  int i = blockIdx.x * 256 + threadIdx.x;
  if (i < 196608) {
    float v = (i < 65536) ? Wq[i] : Wkv[i - 65536];
    wcat[i] = f2bf(v);
  } else {
    int j = i - 196608;
    wpb[j] = f2bf(Wp[j]);
  }
}

// x fp32 [33554432] -> xb bf16, 8 elems/thread
__global__ __launch_bounds__(256) void convert_x(const float* __restrict__ x,
                                                 unsigned short* __restrict__ xb) {
  size_t i = ((size_t)blockIdx.x * 256 + threadIdx.x) * 8;
  const float4* g = (const float4*)(x + i);
  float4 a = g[0], b = g[1];
  uint4 u;
  u.x = pack2(a.x, a.y);
  u.y = pack2(a.z, a.w);
  u.z = pack2(b.x, b.y);
  u.w = pack2(b.z, b.w);
  *(uint4*)(xb + i) = u;
}

// ---------------------------------------------------------------------------
// GEMM  C[M x Nout] = A[M x 256] * W[Nout x 256]^T, bf16 MFMA 16x16x32
// MODE 0: A bf16 (gload_lds), epilogue elu+1 -> Q/K/V bf16
// MODE 1: A bf16 (gload_lds), epilogue + bias -> out fp32
// MODE 2: A fp32 (reg-stage + pack, fallback), epilogue -> Q/K/V
// tile 128x128, BK=64, 256 threads (4 waves, 2x2), XCD-swizzled grid
// ---------------------------------------------------------------------------
template<int MODE>
__global__ __launch_bounds__(256) void gemm_bt(
    const void* __restrict__ Aptr,
    const unsigned short* __restrict__ Bw,
    unsigned short* __restrict__ Q,
    unsigned short* __restrict__ Kb,
    unsigned short* __restrict__ Vb,
    float* __restrict__ out,
    const float* __restrict__ bias,
    int ntiles_n) {
  const int nwg = gridDim.x;            // multiple of 8
  const int cpx = nwg >> 3;
  const int bid = blockIdx.x;
  const int swz = (bid & 7) * cpx + (bid >> 3);
  const int bx = swz % ntiles_n;
  const int by = swz / ntiles_n;
  const int brow = by * 128, bcol = bx * 128;
  const int t = threadIdx.x;
  const int lane = t & 63, w = t >> 6;
  const int wm = w >> 1, wn = w & 1;

  __shared__ __align__(16) unsigned char ldsA[128 * 128];  // 128 rows x 128B
  __shared__ __align__(16) unsigned char ldsB[128 * 128];

  f32x4 acc[4][4] = {};

  // gload staging geometry: per seg (8 rows x 128B = 1KB = one wave instr)
  const int rl = lane >> 3;                          // 0..7 row within seg
  const int swcol = (((lane & 7) ^ rl) << 4);        // pre-swizzled src col byte
  // MODE2 reg-staging geometry
  const int sub = t & 7;
  const int r0 = t >> 3;

  for (int kt = 0; kt < 4; ++kt) {
    if (MODE == 2) {
      const float* xp = (const float*)Aptr;
#pragma unroll
      for (int p = 0; p < 4; ++p) {
        int row = p * 32 + r0;
        const float4* g =
            (const float4*)(xp + (size_t)(brow + row) * 256 + kt * 64 + sub * 8);
        float4 u0 = g[0], u1 = g[1];
        uint4 u;
        u.x = pack2(u0.x, u0.y);
        u.y = pack2(u0.z, u0.w);
        u.z = pack2(u1.x, u1.y);
        u.w = pack2(u1.z, u1.w);
        int byteo = row * 128 + ((sub * 16) ^ ((row & 7) << 4));
        *(uint4*)(ldsA + byteo) = u;
      }
#pragma unroll
      for (int p = 0; p < 4; ++p) {
        int row = p * 32 + r0;
        uint4 u = *(const uint4*)(Bw + (size_t)(bcol + row) * 256 + kt * 64 + sub * 8);
        int byteo = row * 128 + ((sub * 16) ^ ((row & 7) << 4));
        *(uint4*)(ldsB + byteo) = u;
      }
    } else {
      const unsigned short* A = (const unsigned short*)Aptr;
#pragma unroll
      for (int s = 0; s < 4; ++s) {
        int row = w * 32 + s * 8;   // wave-uniform seg base
        gload16((const char*)(A + (size_t)(brow + row + rl) * 256) + kt * 128 + swcol,
                ldsA + row * 128);
        gload16((const char*)(Bw + (size_t)(bcol + row + rl) * 256) + kt * 128 + swcol,
                ldsB + row * 128);
      }
    }
    __syncthreads();

    const int fr = lane & 15, fq = lane >> 4;
#pragma unroll
    for (int kk = 0; kk < 2; ++kk) {
      int kbyte = kk * 64 + fq * 16;
      short8 af[4], bfr[4];
#pragma unroll
      for (int i = 0; i < 4; ++i) {
        int ra = wm * 64 + i * 16 + fr;
        af[i] = *(const short8*)(ldsA + ra * 128 + (kbyte ^ ((ra & 7) << 4)));
        int rb = wn * 64 + i * 16 + fr;
        bfr[i] = *(const short8*)(ldsB + rb * 128 + (kbyte ^ ((rb & 7) << 4)));
      }
#pragma unroll
      for (int i = 0; i < 4; ++i)
#pragma unroll
        for (int j = 0; j < 4; ++j)
          acc[i][j] = __builtin_amdgcn_mfma_f32_16x16x32_bf16(af[i], bfr[j],
                                                              acc[i][j], 0, 0, 0);
    }
    __syncthreads();
  }

  const int fr = lane & 15, fq = lane >> 4;
#pragma unroll
  for (int i = 0; i < 4; ++i) {
#pragma unroll
    for (int j = 0; j < 4; ++j) {
#pragma unroll
      for (int reg = 0; reg < 4; ++reg) {
        int gm = brow + wm * 64 + i * 16 + fq * 4 + reg;
        int gn = bcol + wn * 64 + j * 16 + fr;
        float val = acc[i][j][reg];
        if (MODE != 1) {
          if (gn < 512) val = (val > 0.f) ? (val + 1.f) : __expf(val);
          unsigned short bv = f2bf(val);
          size_t rowoff = (size_t)gm * 256;
          if (gn < 256)
            Q[rowoff + gn] = bv;
          else if (gn < 512)
            Kb[rowoff + gn - 256] = bv;
          else
            Vb[rowoff + gn - 512] = bv;
        } else {
          out[(size_t)gm * 256 + gn] = val + bias[gn];
        }
      }
    }
  }
}

// ---------------------------------------------------------------------------
// ctx partials: block = (b, head-pair hp, chunk): partial k^T v for 2 heads
// grid 512 = 8b * 4hp * 16chunk, 256 threads. 128B-aligned column reads.
// ---------------------------------------------------------------------------
__global__ __launch_bounds__(256) void ctx_partial(
    const unsigned short* __restrict__ Kb, const unsigned short* __restrict__ Vb,
    float* __restrict__ pctx, float* __restrict__ pksum) {
  const int blk = blockIdx.x;
  const int b = blk >> 6;
  const int hp = (blk >> 4) & 3;
  const int chunk = blk & 15;
  const int t = threadIdx.x;
  const size_t rowbase = (size_t)b * 16384 + (size_t)chunk * 1024;
  const int colbase = hp * 64;

  __shared__ __align__(16) unsigned short kt_[64][64];
  __shared__ __align__(16) unsigned short vt_[64][64];

  const int d = t >> 3;          // 0..31
  const int e4 = (t & 7) * 4;    // 0..28
  float a0[4] = {0.f, 0.f, 0.f, 0.f}, a1[4] = {0.f, 0.f, 0.f, 0.f};
  float ks0 = 0.f, ks1 = 0.f;

  const int lrow = t >> 3;       // 0..31
  const int lcol = (t & 7) * 8;  // 0..56
  for (int pass = 0; pass < 16; ++pass) {
#pragma unroll
    for (int hf = 0; hf < 2; ++hf) {
      size_t row = rowbase + pass * 64 + hf * 32 + lrow;
      *(uint4*)&kt_[hf * 32 + lrow][lcol] = *(const uint4*)(Kb + row * 256 + colbase + lcol);
      *(uint4*)&vt_[hf * 32 + lrow][lcol] = *(const uint4*)(Vb + row * 256 + colbase + lcol);
    }
    __syncthreads();
#pragma unroll 4
    for (int n = 0; n < 64; ++n) {
      float k0 = bf2f(kt_[n][d]);
      float k1 = bf2f(kt_[n][32 + d]);
      if ((t & 7) == 0) { ks0 += k0; ks1 += k1; }
      uint2 w0 = *(const uint2*)&vt_[n][e4];
      uint2 w1 = *(const uint2*)&vt_[n][32 + e4];
      float v00 = __uint_as_float(w0.x << 16), v01 = __uint_as_float(w0.x & 0xffff0000u);
      float v02 = __uint_as_float(w0.y << 16), v03 = __uint_as_float(w0.y & 0xffff0000u);
      float v10 = __uint_as_float(w1.x << 16), v11 = __uint_as_float(w1.x & 0xffff0000u);
      float v12 = __uint_as_float(w1.y << 16), v13 = __uint_as_float(w1.y & 0xffff0000u);
      a0[0] += k0 * v00; a0[1] += k0 * v01; a0[2] += k0 * v02; a0[3] += k0 * v03;
      a1[0] += k1 * v10; a1[1] += k1 * v11; a1[2] += k1 * v12; a1[3] += k1 * v13;
    }
    __syncthreads();
  }
  float* p0 = pctx + (size_t)blk * 2048 + d * 32 + e4;
  p0[0] = a0[0]; p0[1] = a0[1]; p0[2] = a0[2]; p0[3] = a0[3];
  float* p1 = p0 + 1024;
  p1[0] = a1[0]; p1[1] = a1[1]; p1[2] = a1[2]; p1[3] = a1[3];
  if ((t & 7) == 0) {
    pksum[blk * 64 + d] = ks0;
    pksum[blk * 64 + 32 + d] = ks1;
  }
}

// ---------------------------------------------------------------------------
// ctx final reduce: 64 blocks (one per bh), 16 chunk-partials each
// ---------------------------------------------------------------------------
__global__ __launch_bounds__(256) void ctx_final(
    const float* __restrict__ pctx, const float* __restrict__ pksum,
    float* __restrict__ ctx, float* __restrict__ ksum) {
  int bh = blockIdx.x;
  int b = bh >> 3, h = bh & 7, hp = h >> 1, hh = h & 1;
  int t = threadIdx.x;
  float s0 = 0.f, s1 = 0.f, s2 = 0.f, s3 = 0.f;
  for (int j = 0; j < 16; ++j) {
    const float* p = pctx + ((size_t)((b * 4 + hp) * 16 + j)) * 2048 + hh * 1024 + t * 4;
    s0 += p[0]; s1 += p[1]; s2 += p[2]; s3 += p[3];
  }
  float* c = ctx + ((size_t)bh << 10) + t * 4;
  c[0] = s0; c[1] = s1; c[2] = s2; c[3] = s3;
  if (t < 32) {
    float s = 0.f;
    for (int j = 0; j < 16; ++j) s += pksum[((b * 4 + hp) * 16 + j) * 64 + hh * 32 + t];
    ksum[bh * 32 + t] = s;
  }
}

// ---------------------------------------------------------------------------
// attn: Dinv[r][h] = 1/max(sum_d q[r][h,d]*ksum[h,d], 1e-6) (per-head)
//       attn[r][h,e] = Dinv[r][h] * sum_d q[r][h,d]*ctx[h][d][e]
// ---------------------------------------------------------------------------
__global__ __launch_bounds__(256) void attn_kernel(
    const unsigned short* __restrict__ Q, const float* __restrict__ ctx,
    const float* __restrict__ ksum, unsigned short* __restrict__ attnb) {
  const int t = threadIdx.x;
  const size_t row0 = (size_t)blockIdx.x * 64;
  const int b = (int)(row0 >> 14);
  const int h = t >> 5, e = t & 31;

  __shared__ float qf[64][288];
  __shared__ float ksumL[288];
  __shared__ float Dinv_s[64][8];

  float creg[32];
  const float* cbase = ctx + ((size_t)(b * 8 + h) << 10) + e;
#pragma unroll
  for (int d2 = 0; d2 < 32; ++d2) creg[d2] = cbase[d2 * 32];

  ksumL[h * 36 + e] = ksum[(b * 8 + h) * 32 + e];

  const int rl = t >> 5;
  const int c8 = (t & 31) * 8;
#pragma unroll
  for (int p = 0; p < 8; ++p) {
    int r = p * 8 + rl;
    uint4 u = *(const uint4*)(Q + (row0 + r) * 256 + c8);
    const unsigned short* us = (const unsigned short*)&u;
    float* dst = &qf[r][(c8 >> 5) * 36 + (c8 & 31)];
#pragma unroll
    for (int q2 = 0; q2 < 8; ++q2) dst[q2] = bf2f(us[q2]);
  }
  __syncthreads();

#pragma unroll
  for (int ii = 0; ii < 2; ++ii) {
    int idx = t + ii * 256;
    int r = idx >> 3, hh = idx & 7;
    const float* qr = &qf[r][hh * 36];
    const float* ks = &ksumL[hh * 36];
    float s = 0.f;
#pragma unroll
    for (int d2 = 0; d2 < 32; ++d2) s += qr[d2] * ks[d2];
    Dinv_s[r][hh] = 1.f / fmaxf(s, 1e-6f);
  }
  __syncthreads();

  for (int r = 0; r < 64; ++r) {
    const float* qr = &qf[r][h * 36];
    float s = 0.f;
#pragma unroll
    for (int d2 = 0; d2 < 32; ++d2) s += qr[d2] * creg[d2];
    attnb[(row0 + r) * 256 + t] = f2bf(s * Dinv_s[r][h]);
  }
}

// ---------------------------------------------------------------------------
extern "C" void kernel_launch(void* const* d_in, const int* in_sizes, int n_in,
                              void* d_out, int out_size, void* d_ws, size_t ws_size,
                              hipStream_t stream) {
  const float* x = (const float*)d_in[0];
  const float* Wq = (const float*)d_in[1];
  const float* Wkv = (const float*)d_in[2];
  const float* Wproj = (const float*)d_in[3];
  const float* bproj = (const float*)d_in[4];
  float* out = (float*)d_out;

  char* ws = (char*)d_ws;
  unsigned short* Q = (unsigned short*)(ws);                 // 67,108,864
  unsigned short* Kb = (unsigned short*)(ws + 67108864);     // 67,108,864
  unsigned short* Vb = (unsigned short*)(ws + 134217728);    // 67,108,864
  unsigned short* wcat = (unsigned short*)(ws + 201326592);  // 393,216
  unsigned short* wpb = (unsigned short*)(ws + 201719808);   // 131,072
  unsigned short* xb = (unsigned short*)(ws + 201850880);    // 67,108,864 (dead after qkv gemm)
  // pctx/pksum/ctx/ksum alias the xb region (used only after qkv gemm)
  float* pctx = (float*)(ws + 201850880);                    // 4,194,304
  float* pksum = (float*)(ws + 206045184);                   // 131,072
  float* ctx = (float*)(ws + 206176256);                     // 262,144
  float* ksum = (float*)(ws + 206438400);                    // 8,192
  unsigned short* attnb = Kb;  // reuse K buffer after ctx reduction

  const bool big = ws_size >= (size_t)268959744;

  prep_weights<<<1024, 256, 0, stream>>>(Wq, Wkv, Wproj, wcat, wpb);
  if (big) {
    convert_x<<<16384, 256, 0, stream>>>(x, xb);
    gemm_bt<0><<<6144, 256, 0, stream>>>(xb, wcat, Q, Kb, Vb, nullptr, nullptr, 6);
  } else {
    gemm_bt<2><<<6144, 256, 0, stream>>>(x, wcat, Q, Kb, Vb, nullptr, nullptr, 6);
  }
  ctx_partial<<<512, 256, 0, stream>>>(Kb, Vb, pctx, pksum);
  ctx_final<<<64, 256, 0, stream>>>(pctx, pksum, ctx, ksum);
  attn_kernel<<<2048, 256, 0, stream>>>(Q, ctx, ksum, attnb);
  gemm_bt<1><<<2048, 256, 0, stream>>>(attnb, wpb, nullptr, nullptr, nullptr, out,
                                       bproj, 2);
}

// Round 4
// 361.849 us; speedup vs baseline: 1.1693x; 1.0167x over previous
//
#include <hip/hip_runtime.h>
#include <hip/hip_bf16.h>
#include <cstdint>
#include <cstddef>

typedef __attribute__((ext_vector_type(8))) short short8;
typedef __attribute__((ext_vector_type(4))) float f32x4;

#define DEVI static __device__ __forceinline__

DEVI unsigned short f2bf(float f) {
  unsigned u = __float_as_uint(f);
  unsigned r = u + 0x7fffu + ((u >> 16) & 1u);
  return (unsigned short)(r >> 16);
}
DEVI float bf2f(unsigned short s) {
  return __uint_as_float(((unsigned)s) << 16);
}
DEVI unsigned pack2(float a, float b) {
  return (unsigned)f2bf(a) | ((unsigned)f2bf(b) << 16);
}

DEVI void gload16(const void* g, void* l) {
  __builtin_amdgcn_global_load_lds(
      (__attribute__((address_space(1))) void*)g,
      (__attribute__((address_space(3))) void*)l, 16, 0, 0);
}

// ---------------------------------------------------------------------------
// prep_all: fused  x->xb bf16 (blocks 0..16383)  +  weight converts (16384..)
// ---------------------------------------------------------------------------
__global__ __launch_bounds__(256) void prep_all(
    const float* __restrict__ x, const float* __restrict__ Wq,
    const float* __restrict__ Wkv, const float* __restrict__ Wp,
    unsigned short* __restrict__ xb, unsigned short* __restrict__ wcat,
    unsigned short* __restrict__ wpb) {
  int bidx = blockIdx.x;
  if (bidx < 16384) {
    size_t i = ((size_t)bidx * 256 + threadIdx.x) * 8;
    const float4* g = (const float4*)(x + i);
    float4 a = g[0], b = g[1];
    uint4 u;
    u.x = pack2(a.x, a.y);
    u.y = pack2(a.z, a.w);
    u.z = pack2(b.x, b.y);
    u.w = pack2(b.z, b.w);
    *(uint4*)(xb + i) = u;
  } else {
    int i = (bidx - 16384) * 256 + threadIdx.x;
    if (i < 196608) {
      float v = (i < 65536) ? Wq[i] : Wkv[i - 65536];
      wcat[i] = f2bf(v);
    } else {
      int j = i - 196608;
      wpb[j] = f2bf(Wp[j]);
    }
  }
}

// ---------------------------------------------------------------------------
// GEMM  C[M x Nout] = A[M x 256] * W[Nout x 256]^T, bf16 MFMA 16x16x32
// 2-phase double-buffered gload_lds staging (T3-minimum schedule).
// MODE 0: A bf16, epilogue elu+1 -> Q/K/V bf16
// MODE 1: A bf16, epilogue + bias -> out fp32
// MODE 2: A fp32 (reg-stage fallback, single-buffered)
// tile 128x128, BK=64, 256 threads (4 waves, 2x2), XCD-swizzled grid
// ---------------------------------------------------------------------------
template<int MODE>
__global__ __launch_bounds__(256) void gemm_bt(
    const void* __restrict__ Aptr,
    const unsigned short* __restrict__ Bw,
    unsigned short* __restrict__ Q,
    unsigned short* __restrict__ Kb,
    unsigned short* __restrict__ Vb,
    float* __restrict__ out,
    const float* __restrict__ bias,
    int ntiles_n) {
  const int nwg = gridDim.x;            // multiple of 8
  const int cpx = nwg >> 3;
  const int bid = blockIdx.x;
  const int swz = (bid & 7) * cpx + (bid >> 3);
  const int bx = swz % ntiles_n;
  const int by = swz / ntiles_n;
  const int brow = by * 128, bcol = bx * 128;
  const int t = threadIdx.x;
  const int lane = t & 63, w = t >> 6;
  const int wm = w >> 1, wn = w & 1;

  __shared__ __align__(16) unsigned char ldsA[2][128 * 128];  // 2 x 16KB
  __shared__ __align__(16) unsigned char ldsB[2][128 * 128];  // 2 x 16KB

  f32x4 acc[4][4] = {};

  const int rl = lane >> 3;                    // row-in-seg 0..7
  const int swcol = (((lane & 7) ^ rl) << 4);  // pre-swizzled src col byte
  const int fr = lane & 15, fq = lane >> 4;

  const unsigned short* A = (const unsigned short*)Aptr;

  auto stage = [&](int buf, int kt) {
#pragma unroll
    for (int s = 0; s < 4; ++s) {
      int row = w * 32 + s * 8;  // wave-uniform seg base
      gload16((const char*)(A + (size_t)(brow + row + rl) * 256) + kt * 128 + swcol,
              &ldsA[buf][row * 128]);
      gload16((const char*)(Bw + (size_t)(bcol + row + rl) * 256) + kt * 128 + swcol,
              &ldsB[buf][row * 128]);
    }
  };

  auto compute = [&](int buf) {
#pragma unroll
    for (int kk = 0; kk < 2; ++kk) {
      int kbyte = kk * 64 + fq * 16;
      short8 af[4], bfr[4];
#pragma unroll
      for (int i = 0; i < 4; ++i) {
        int ra = wm * 64 + i * 16 + fr;
        af[i] = *(const short8*)(&ldsA[buf][ra * 128 + (kbyte ^ ((ra & 7) << 4))]);
        int rb = wn * 64 + i * 16 + fr;
        bfr[i] = *(const short8*)(&ldsB[buf][rb * 128 + (kbyte ^ ((rb & 7) << 4))]);
      }
#pragma unroll
      for (int i = 0; i < 4; ++i)
#pragma unroll
        for (int j = 0; j < 4; ++j)
          acc[i][j] = __builtin_amdgcn_mfma_f32_16x16x32_bf16(af[i], bfr[j],
                                                              acc[i][j], 0, 0, 0);
    }
  };

  if (MODE == 2) {
    // fallback: fp32 reg-stage, single-buffered in buf 0
    const int sub = t & 7;
    const int r0 = t >> 3;
    const float* xp = (const float*)Aptr;
    for (int kt = 0; kt < 4; ++kt) {
#pragma unroll
      for (int p = 0; p < 4; ++p) {
        int row = p * 32 + r0;
        const float4* g =
            (const float4*)(xp + (size_t)(brow + row) * 256 + kt * 64 + sub * 8);
        float4 u0 = g[0], u1 = g[1];
        uint4 u;
        u.x = pack2(u0.x, u0.y);
        u.y = pack2(u0.z, u0.w);
        u.z = pack2(u1.x, u1.y);
        u.w = pack2(u1.z, u1.w);
        *(uint4*)(&ldsA[0][row * 128 + ((sub * 16) ^ ((row & 7) << 4))]) = u;
      }
#pragma unroll
      for (int p = 0; p < 4; ++p) {
        int row = p * 32 + r0;
        uint4 u = *(const uint4*)(Bw + (size_t)(bcol + row) * 256 + kt * 64 + sub * 8);
        *(uint4*)(&ldsB[0][row * 128 + ((sub * 16) ^ ((row & 7) << 4))]) = u;
      }
      __syncthreads();
      compute(0);
      __syncthreads();
    }
  } else {
    // 2-phase: prefetch kt+1 into the other buffer before computing kt
    stage(0, 0);
    __syncthreads();
    stage(1, 1);
    compute(0);
    __syncthreads();
    stage(0, 2);
    compute(1);
    __syncthreads();
    stage(1, 3);
    compute(0);
    __syncthreads();
    compute(1);
  }

  // --- epilogue ---
  if (MODE != 1) {
    unsigned short* dst;
    int cofs;
    bool do_elu;
    if (bcol < 256) {
      dst = Q; cofs = bcol; do_elu = true;
    } else if (bcol < 512) {
      dst = Kb; cofs = bcol - 256; do_elu = true;
    } else {
      dst = Vb; cofs = bcol - 512; do_elu = false;
    }
#pragma unroll
    for (int i = 0; i < 4; ++i)
#pragma unroll
      for (int j = 0; j < 4; ++j)
#pragma unroll
        for (int reg = 0; reg < 4; ++reg) {
          int gm = brow + wm * 64 + i * 16 + fq * 4 + reg;
          int cn = cofs + wn * 64 + j * 16 + fr;
          float val = acc[i][j][reg];
          if (do_elu) val = (val > 0.f) ? (val + 1.f) : __expf(val);
          dst[(size_t)gm * 256 + cn] = f2bf(val);
        }
  } else {
#pragma unroll
    for (int i = 0; i < 4; ++i)
#pragma unroll
      for (int j = 0; j < 4; ++j)
#pragma unroll
        for (int reg = 0; reg < 4; ++reg) {
          int gm = brow + wm * 64 + i * 16 + fq * 4 + reg;
          int gn = bcol + wn * 64 + j * 16 + fr;
          out[(size_t)gm * 256 + gn] = acc[i][j][reg] + bias[gn];
        }
  }
}

// ---------------------------------------------------------------------------
// ctx partials: block = (b, head-pair hp, chunk): partial k^T v for 2 heads
// grid 512 = 8b * 4hp * 16chunk, 256 threads. 128B-aligned column reads.
// ---------------------------------------------------------------------------
__global__ __launch_bounds__(256) void ctx_partial(
    const unsigned short* __restrict__ Kb, const unsigned short* __restrict__ Vb,
    float* __restrict__ pctx, float* __restrict__ pksum) {
  const int blk = blockIdx.x;
  const int b = blk >> 6;
  const int hp = (blk >> 4) & 3;
  const int chunk = blk & 15;
  const int t = threadIdx.x;
  const size_t rowbase = (size_t)b * 16384 + (size_t)chunk * 1024;
  const int colbase = hp * 64;

  __shared__ __align__(16) unsigned short kt_[64][64];
  __shared__ __align__(16) unsigned short vt_[64][64];

  const int d = t >> 3;
  const int e4 = (t & 7) * 4;
  float a0[4] = {0.f, 0.f, 0.f, 0.f}, a1[4] = {0.f, 0.f, 0.f, 0.f};
  float ks0 = 0.f, ks1 = 0.f;

  const int lrow = t >> 3;
  const int lcol = (t & 7) * 8;
  for (int pass = 0; pass < 16; ++pass) {
#pragma unroll
    for (int hf = 0; hf < 2; ++hf) {
      size_t row = rowbase + pass * 64 + hf * 32 + lrow;
      *(uint4*)&kt_[hf * 32 + lrow][lcol] = *(const uint4*)(Kb + row * 256 + colbase + lcol);
      *(uint4*)&vt_[hf * 32 + lrow][lcol] = *(const uint4*)(Vb + row * 256 + colbase + lcol);
    }
    __syncthreads();
#pragma unroll 4
    for (int n = 0; n < 64; ++n) {
      float k0 = bf2f(kt_[n][d]);
      float k1 = bf2f(kt_[n][32 + d]);
      if ((t & 7) == 0) { ks0 += k0; ks1 += k1; }
      uint2 w0 = *(const uint2*)&vt_[n][e4];
      uint2 w1 = *(const uint2*)&vt_[n][32 + e4];
      float v00 = __uint_as_float(w0.x << 16), v01 = __uint_as_float(w0.x & 0xffff0000u);
      float v02 = __uint_as_float(w0.y << 16), v03 = __uint_as_float(w0.y & 0xffff0000u);
      float v10 = __uint_as_float(w1.x << 16), v11 = __uint_as_float(w1.x & 0xffff0000u);
      float v12 = __uint_as_float(w1.y << 16), v13 = __uint_as_float(w1.y & 0xffff0000u);
      a0[0] += k0 * v00; a0[1] += k0 * v01; a0[2] += k0 * v02; a0[3] += k0 * v03;
      a1[0] += k1 * v10; a1[1] += k1 * v11; a1[2] += k1 * v12; a1[3] += k1 * v13;
    }
    __syncthreads();
  }
  float* p0 = pctx + (size_t)blk * 2048 + d * 32 + e4;
  p0[0] = a0[0]; p0[1] = a0[1]; p0[2] = a0[2]; p0[3] = a0[3];
  float* p1 = p0 + 1024;
  p1[0] = a1[0]; p1[1] = a1[1]; p1[2] = a1[2]; p1[3] = a1[3];
  if ((t & 7) == 0) {
    pksum[blk * 64 + d] = ks0;
    pksum[blk * 64 + 32 + d] = ks1;
  }
}

// ---------------------------------------------------------------------------
// ctx final reduce: 64 blocks (one per bh), 16 chunk-partials each
// ---------------------------------------------------------------------------
__global__ __launch_bounds__(256) void ctx_final(
    const float* __restrict__ pctx, const float* __restrict__ pksum,
    float* __restrict__ ctx, float* __restrict__ ksum) {
  int bh = blockIdx.x;
  int b = bh >> 3, h = bh & 7, hp = h >> 1, hh = h & 1;
  int t = threadIdx.x;
  float s0 = 0.f, s1 = 0.f, s2 = 0.f, s3 = 0.f;
  for (int j = 0; j < 16; ++j) {
    const float* p = pctx + ((size_t)((b * 4 + hp) * 16 + j)) * 2048 + hh * 1024 + t * 4;
    s0 += p[0]; s1 += p[1]; s2 += p[2]; s3 += p[3];
  }
  float* c = ctx + ((size_t)bh << 10) + t * 4;
  c[0] = s0; c[1] = s1; c[2] = s2; c[3] = s3;
  if (t < 32) {
    float s = 0.f;
    for (int j = 0; j < 16; ++j) s += pksum[((b * 4 + hp) * 16 + j) * 64 + hh * 32 + t];
    ksum[bh * 32 + t] = s;
  }
}

// ---------------------------------------------------------------------------
// attn: Dinv[r][h] = 1/max(sum_d q[r][h,d]*ksum[h,d], 1e-6) (per-head)
//       attn[r][h,e] = Dinv[r][h] * sum_d q[r][h,d]*ctx[h][d][e]
// ---------------------------------------------------------------------------
__global__ __launch_bounds__(256) void attn_kernel(
    const unsigned short* __restrict__ Q, const float* __restrict__ ctx,
    const float* __restrict__ ksum, unsigned short* __restrict__ attnb) {
  const int t = threadIdx.x;
  const size_t row0 = (size_t)blockIdx.x * 64;
  const int b = (int)(row0 >> 14);
  const int h = t >> 5, e = t & 31;

  __shared__ float qf[64][288];
  __shared__ float ksumL[288];
  __shared__ float Dinv_s[64][8];

  float creg[32];
  const float* cbase = ctx + ((size_t)(b * 8 + h) << 10) + e;
#pragma unroll
  for (int d2 = 0; d2 < 32; ++d2) creg[d2] = cbase[d2 * 32];

  ksumL[h * 36 + e] = ksum[(b * 8 + h) * 32 + e];

  const int rl = t >> 5;
  const int c8 = (t & 31) * 8;
#pragma unroll
  for (int p = 0; p < 8; ++p) {
    int r = p * 8 + rl;
    uint4 u = *(const uint4*)(Q + (row0 + r) * 256 + c8);
    const unsigned short* us = (const unsigned short*)&u;
    float* dst = &qf[r][(c8 >> 5) * 36 + (c8 & 31)];
#pragma unroll
    for (int q2 = 0; q2 < 8; ++q2) dst[q2] = bf2f(us[q2]);
  }
  __syncthreads();

#pragma unroll
  for (int ii = 0; ii < 2; ++ii) {
    int idx = t + ii * 256;
    int r = idx >> 3, hh = idx & 7;
    const float* qr = &qf[r][hh * 36];
    const float* ks = &ksumL[hh * 36];
    float s = 0.f;
#pragma unroll
    for (int d2 = 0; d2 < 32; ++d2) s += qr[d2] * ks[d2];
    Dinv_s[r][hh] = 1.f / fmaxf(s, 1e-6f);
  }
  __syncthreads();

  for (int r = 0; r < 64; ++r) {
    const float* qr = &qf[r][h * 36];
    float s = 0.f;
#pragma unroll
    for (int d2 = 0; d2 < 32; ++d2) s += qr[d2] * creg[d2];
    attnb[(row0 + r) * 256 + t] = f2bf(s * Dinv_s[r][h]);
  }
}

// ---------------------------------------------------------------------------
extern "C" void kernel_launch(void* const* d_in, const int* in_sizes, int n_in,
                              void* d_out, int out_size, void* d_ws, size_t ws_size,
                              hipStream_t stream) {
  const float* x = (const float*)d_in[0];
  const float* Wq = (const float*)d_in[1];
  const float* Wkv = (const float*)d_in[2];
  const float* Wproj = (const float*)d_in[3];
  const float* bproj = (const float*)d_in[4];
  float* out = (float*)d_out;

  char* ws = (char*)d_ws;
  unsigned short* Q = (unsigned short*)(ws);                 // 67,108,864
  unsigned short* Kb = (unsigned short*)(ws + 67108864);     // 67,108,864
  unsigned short* Vb = (unsigned short*)(ws + 134217728);    // 67,108,864
  unsigned short* wcat = (unsigned short*)(ws + 201326592);  // 393,216
  unsigned short* wpb = (unsigned short*)(ws + 201719808);   // 131,072
  unsigned short* xb = (unsigned short*)(ws + 201850880);    // 67,108,864 (dead after qkv gemm)
  float* pctx = (float*)(ws + 201850880);                    // aliases xb
  float* pksum = (float*)(ws + 206045184);
  float* ctx = (float*)(ws + 206176256);
  float* ksum = (float*)(ws + 206438400);
  unsigned short* attnb = Kb;  // reuse K buffer after ctx reduction

  const bool big = ws_size >= (size_t)268959744;

  if (big) {
    prep_all<<<17408, 256, 0, stream>>>(x, Wq, Wkv, Wproj, xb, wcat, wpb);
    gemm_bt<0><<<6144, 256, 0, stream>>>(xb, wcat, Q, Kb, Vb, nullptr, nullptr, 6);
  } else {
    prep_all<<<1024, 256, 0, stream>>>(nullptr, Wq, Wkv, Wproj, nullptr, wcat, wpb);
    gemm_bt<2><<<6144, 256, 0, stream>>>(x, wcat, Q, Kb, Vb, nullptr, nullptr, 6);
  }
  ctx_partial<<<512, 256, 0, stream>>>(Kb, Vb, pctx, pksum);
  ctx_final<<<64, 256, 0, stream>>>(pctx, pksum, ctx, ksum);
  attn_kernel<<<2048, 256, 0, stream>>>(Q, ctx, ksum, attnb);
  gemm_bt<1><<<2048, 256, 0, stream>>>(attnb, wpb, nullptr, nullptr, nullptr, out,
                                       bproj, 2);
}